// Round 3
// baseline (302.038 us; speedup 1.0000x reference)
//
#include <hip/hip_runtime.h>
#include <hip/hip_bf16.h>

#define NODES 2048
#define DIM   64
#define K_TOP 30
#define BATCH 16
#define BN    (NODES * BATCH)
#define NEGINF (-3.402823466e38f)
#define EPS 1e-5f

// ---------------------------------------------------------------------------
// K1: row norms of embedding  (one wave per row)
// ---------------------------------------------------------------------------
__global__ __launch_bounds__(256) void norms_kernel(const float* __restrict__ w,
                                                    float* __restrict__ nrm) {
    int r = blockIdx.x * 4 + (threadIdx.x >> 6);
    int lane = threadIdx.x & 63;
    float v = w[r * DIM + lane];
    float s = v * v;
    #pragma unroll
    for (int off = 32; off; off >>= 1) s += __shfl_xor(s, off, 64);
    if (lane == 0) nrm[r] = sqrtf(s);
}

// ---------------------------------------------------------------------------
// K2: cosine-similarity row + register-resident top-30 (one block per row).
// Dot phase: all 256 threads, coalesced float4 (unchanged from baseline —
// measured 0 bank conflicts). Selection: wave 0 holds the whole row in
// registers (32 vals/lane, static unroll) and runs 30 barrier-free
// butterfly-argmax extractions. Tie-break: lower index wins (lax.top_k).
// Output is the top-k SET (downstream softmax+sum is permutation-invariant).
// ---------------------------------------------------------------------------
__global__ __launch_bounds__(256) void cos_topk_kernel(const float* __restrict__ w,
                                                       const float* __restrict__ nrm,
                                                       int* __restrict__ topk) {
    const int i = blockIdx.x;
    const int tid = threadIdx.x;
    __shared__ float wi[DIM];
    __shared__ float row[NODES];

    if (tid < DIM) wi[tid] = w[i * DIM + tid];
    __syncthreads();

    const float ni = nrm[i];
    for (int j = tid; j < NODES; j += 256) {
        const float4* wj = (const float4*)(w + j * DIM);
        float acc = 0.f;
        #pragma unroll
        for (int q = 0; q < DIM / 4; ++q) {
            float4 v = wj[q];
            acc = fmaf(v.x, wi[q * 4 + 0], acc);
            acc = fmaf(v.y, wi[q * 4 + 1], acc);
            acc = fmaf(v.z, wi[q * 4 + 2], acc);
            acc = fmaf(v.w, wi[q * 4 + 3], acc);
        }
        row[j] = acc / (ni * nrm[j]);
    }
    __syncthreads();

    if (tid >= 64) return;          // selection is wave-0 only; no later barriers
    const int lane = tid;

    // row -> registers: v[q] = row[q*64 + lane]  (consecutive lanes ->
    // consecutive banks; lanes l,l+32 share a bank = 2-way = free)
    float v[NODES / 64];
    #pragma unroll
    for (int q = 0; q < NODES / 64; ++q) v[q] = row[q * 64 + lane];

    int res = 0;
    for (int t = 0; t < K_TOP; ++t) {
        // local argmax over this lane's 32 values (static unroll, lowest q on tie)
        float lm = v[0];
        int lq = 0;
        #pragma unroll
        for (int q = 1; q < NODES / 64; ++q) {
            bool g = v[q] > lm;
            lm = g ? v[q] : lm;
            lq = g ? q : lq;
        }
        float bv = lm;
        int bj = lq * 64 + lane;
        // wave-wide butterfly argmax; lower j wins on exact tie
        #pragma unroll
        for (int off = 32; off; off >>= 1) {
            float ov = __shfl_xor(bv, off, 64);
            int   oj = __shfl_xor(bj, off, 64);
            if (ov > bv || (ov == bv && oj < bj)) { bv = ov; bj = oj; }
        }
        if (lane == t) res = bj;    // lane t keeps result t -> coalesced store
        // remove winner (static-indexed cndmask; only winner lane matches)
        const int wl = bj & 63, wq = bj >> 6;
        #pragma unroll
        for (int q = 0; q < NODES / 64; ++q)
            if (q == wq && lane == wl) v[q] = NEGINF;
    }
    if (lane < K_TOP) topk[i * K_TOP + lane] = res;
}

// ---------------------------------------------------------------------------
// K3: xl = x @ lin_w ; a_i/a_j per node (fused). One wave per output row.
// ---------------------------------------------------------------------------
__global__ __launch_bounds__(256) void lin_kernel(const float* __restrict__ x,
                                                  const float* __restrict__ lin_w,
                                                  const float* __restrict__ emb,
                                                  const float* __restrict__ att_i,
                                                  const float* __restrict__ att_j,
                                                  const float* __restrict__ att_em_i,
                                                  const float* __restrict__ att_em_j,
                                                  float* __restrict__ xl,
                                                  float* __restrict__ ai,
                                                  float* __restrict__ aj) {
    __shared__ float lw[DIM * DIM];   // 16 KiB
    __shared__ float xs[16 * DIM];    // 4 KiB
    const int tid = threadIdx.x;
    const int wave = tid >> 6;
    const int lane = tid & 63;
    const int row0 = blockIdx.x * 16;

    for (int t = tid; t < DIM * DIM; t += 256) lw[t] = lin_w[t];
    for (int t = tid; t < 16 * DIM; t += 256) xs[t] = x[row0 * DIM + t];
    __syncthreads();

    for (int rr = wave; rr < 16; rr += 4) {
        const int r = row0 + rr;
        float acc = 0.f;
        #pragma unroll
        for (int f = 0; f < DIM; ++f)
            acc = fmaf(xs[rr * DIM + f], lw[f * DIM + lane], acc);  // stride-64: 2/bank = free
        xl[r * DIM + lane] = acc;

        const int i = r & (NODES - 1);
        const float em = emb[i * DIM + lane];
        float ti = acc * att_i[lane] + em * att_em_i[lane];
        float tj = acc * att_j[lane] + em * att_em_j[lane];
        #pragma unroll
        for (int off = 32; off; off >>= 1) {
            ti += __shfl_xor(ti, off, 64);
            tj += __shfl_xor(tj, off, 64);
        }
        if (lane == 0) { ai[r] = ti; aj[r] = tj; }
    }
}

// ---------------------------------------------------------------------------
// K4: per-node fused GAT aggregate + BN1 + ReLU + emb-mul + BN2 + ReLU + readout
// one 64-lane wave per target node; lane == feature dim
// ---------------------------------------------------------------------------
__global__ __launch_bounds__(256) void agg_kernel(const int* __restrict__ topk,
                                                  const float* __restrict__ xl,
                                                  const float* __restrict__ ai,
                                                  const float* __restrict__ aj,
                                                  const float* __restrict__ emb,
                                                  const float* __restrict__ gnn_bias,
                                                  const float* __restrict__ g1, const float* __restrict__ b1,
                                                  const float* __restrict__ m1, const float* __restrict__ v1,
                                                  const float* __restrict__ g2, const float* __restrict__ b2,
                                                  const float* __restrict__ m2, const float* __restrict__ v2,
                                                  const float* __restrict__ out_w,
                                                  const float* __restrict__ out_b,
                                                  float* __restrict__ y) {
    const int e = blockIdx.x * 4 + (threadIdx.x >> 6);
    const int lane = threadIdx.x & 63;
    const int i = e & (NODES - 1);
    const int b = e >> 11;

    const float a_ie = ai[e];
    int nbr = 0;
    float raw = NEGINF;
    if (lane < K_TOP) {
        nbr = (b << 11) + topk[i * K_TOP + lane];
        float r0 = a_ie + aj[nbr];
        raw = (r0 >= 0.f) ? r0 : 0.2f * r0;   // leaky_relu(0.2)
    }
    float m = raw;
    #pragma unroll
    for (int off = 32; off; off >>= 1) m = fmaxf(m, __shfl_xor(m, off, 64));
    float p = (lane < K_TOP) ? __expf(raw - m) : 0.f;
    float s = p;
    #pragma unroll
    for (int off = 32; off; off >>= 1) s += __shfl_xor(s, off, 64);
    const float inv = 1.f / s;

    float acc = 0.f;
    #pragma unroll
    for (int k = 0; k < K_TOP; ++k) {
        const float pk = __shfl(p, k, 64);
        const int nb = __shfl(nbr, k, 64);
        acc = fmaf(pk, xl[nb * DIM + lane], acc);  // 256B coalesced gather, L2-resident
    }

    float o = acc * inv + gnn_bias[lane];
    o = (o - m1[lane]) * rsqrtf(v1[lane] + EPS) * g1[lane] + b1[lane];
    o = fmaxf(o, 0.f);
    float h = o * emb[i * DIM + lane];
    h = (h - m2[lane]) * rsqrtf(v2[lane] + EPS) * g2[lane] + b2[lane];
    h = fmaxf(h, 0.f);
    float t = h * out_w[lane];
    #pragma unroll
    for (int off = 32; off; off >>= 1) t += __shfl_xor(t, off, 64);
    if (lane == 0) y[e] = t + out_b[0];
}

// ---------------------------------------------------------------------------
extern "C" void kernel_launch(void* const* d_in, const int* in_sizes, int n_in,
                              void* d_out, int out_size, void* d_ws, size_t ws_size,
                              hipStream_t stream) {
    const float* data      = (const float*)d_in[0];
    // d_in[1] org_edge_index: unused (prior_graph dynamic top-k path)
    const float* emb       = (const float*)d_in[2];
    const float* lin_w     = (const float*)d_in[3];
    const float* att_i     = (const float*)d_in[4];
    const float* att_j     = (const float*)d_in[5];
    const float* att_em_i  = (const float*)d_in[6];
    const float* att_em_j  = (const float*)d_in[7];
    const float* gnn_bias  = (const float*)d_in[8];
    const float* bn1_gamma = (const float*)d_in[9];
    const float* bn1_beta  = (const float*)d_in[10];
    const float* bn1_mean  = (const float*)d_in[11];
    const float* bn1_var   = (const float*)d_in[12];
    const float* bn2_gamma = (const float*)d_in[13];
    const float* bn2_beta  = (const float*)d_in[14];
    const float* bn2_mean  = (const float*)d_in[15];
    const float* bn2_var   = (const float*)d_in[16];
    const float* out_w     = (const float*)d_in[17];
    const float* out_b     = (const float*)d_in[18];
    float* y = (float*)d_out;

    // workspace layout (bytes)
    char* ws = (char*)d_ws;
    float* nrm  = (float*)(ws + 0);                    //  2048 f32
    int*   topk = (int*)(ws + 8192);                   //  2048*30 i32
    float* xl   = (float*)(ws + 262144);               //  32768*64 f32 (8 MiB)
    float* ai   = (float*)(ws + 262144 + 8388608);     //  32768 f32
    float* aj   = (float*)(ws + 262144 + 8388608 + 131072);

    norms_kernel<<<NODES / 4, 256, 0, stream>>>(emb, nrm);
    cos_topk_kernel<<<NODES, 256, 0, stream>>>(emb, nrm, topk);
    lin_kernel<<<BN / 16, 256, 0, stream>>>(data, lin_w, emb, att_i, att_j,
                                            att_em_i, att_em_j, xl, ai, aj);
    agg_kernel<<<BN / 4, 256, 0, stream>>>(topk, xl, ai, aj, emb, gnn_bias,
                                           bn1_gamma, bn1_beta, bn1_mean, bn1_var,
                                           bn2_gamma, bn2_beta, bn2_mean, bn2_var,
                                           out_w, out_b, y);
}

// Round 6
// 202.929 us; speedup vs baseline: 1.4884x; 1.4884x over previous
//
#include <hip/hip_runtime.h>
#include <hip/hip_bf16.h>

#define NODES 2048
#define DIM   64
#define K_TOP 30
#define BATCH 16
#define BN    (NODES * BATCH)
#define NEGINF (-3.402823466e38f)
#define EPS 1e-5f
#define TB 64   // cos GEMM tile

// ---------------------------------------------------------------------------
// K1: normalized embedding  wn = w / ||w||_row   (one wave per row)
// ---------------------------------------------------------------------------
__global__ __launch_bounds__(256) void normalize_kernel(const float* __restrict__ w,
                                                        float* __restrict__ wn) {
    int r = blockIdx.x * 4 + (threadIdx.x >> 6);
    int lane = threadIdx.x & 63;
    float v = w[r * DIM + lane];
    float s = v * v;
    #pragma unroll
    for (int off = 32; off; off >>= 1) s += __shfl_xor(s, off, 64);
    wn[r * DIM + lane] = v * rsqrtf(s);
}

// ---------------------------------------------------------------------------
// K2: cos = wn @ wn^T, LDS-tiled fp32 GEMM. 64x64 tile per block, 256 thr,
// 4x4 outputs/thread. (Round-3 ablation showed the old fused kernel was
// latency-bound on per-thread PRIVATE row reads — 64 cache lines per load
// inst. Here all global reads are cooperative/coalesced; LDS +1 pad makes
// A-reads 16-lane broadcasts and B-reads 16-distinct-bank = conflict-free.)
// ---------------------------------------------------------------------------
__global__ __launch_bounds__(256) void cos_kernel(const float* __restrict__ wn,
                                                  float* __restrict__ cosm) {
    __shared__ float As[TB][DIM + 1];
    __shared__ float Bs[TB][DIM + 1];
    const int tid = threadIdx.x;
    const int bi = blockIdx.x, bj = blockIdx.y;

    for (int s = tid; s < TB * DIM; s += 256) {
        int r = s >> 6, d = s & 63;
        As[r][d] = wn[(bi * TB + r) * DIM + d];
        Bs[r][d] = wn[(bj * TB + r) * DIM + d];
    }
    __syncthreads();

    const int ti = tid >> 4, tj = tid & 15;
    float acc[4][4] = {};
    #pragma unroll 16
    for (int k = 0; k < DIM; ++k) {
        float a[4], b[4];
        #pragma unroll
        for (int u = 0; u < 4; ++u) a[u] = As[ti * 4 + u][k];
        #pragma unroll
        for (int v = 0; v < 4; ++v) b[v] = Bs[tj * 4 + v][k];
        #pragma unroll
        for (int u = 0; u < 4; ++u)
            #pragma unroll
            for (int v = 0; v < 4; ++v)
                acc[u][v] = fmaf(a[u], b[v], acc[u][v]);
    }
    #pragma unroll
    for (int u = 0; u < 4; ++u) {
        float4 o = make_float4(acc[u][0], acc[u][1], acc[u][2], acc[u][3]);
        *(float4*)&cosm[(size_t)(bi * TB + ti * 4 + u) * NODES + bj * TB + tj * 4] = o;
    }
}

// ---------------------------------------------------------------------------
// K3: top-30 per row. One wave per row; coalesced row load into 32 regs/lane
// (static unroll -> no scratch), then 30 barrier-free butterfly-argmax
// extractions. Tie-break: lower index wins (lax.top_k). Order of the k
// results is irrelevant downstream (softmax+sum permutation-invariant).
// ---------------------------------------------------------------------------
__global__ __launch_bounds__(256) void topk_kernel(const float* __restrict__ cosm,
                                                   int* __restrict__ topk) {
    const int i = blockIdx.x * 4 + (threadIdx.x >> 6);
    const int lane = threadIdx.x & 63;
    const float* row = cosm + (size_t)i * NODES;

    float v[NODES / 64];
    #pragma unroll
    for (int q = 0; q < NODES / 64; ++q) v[q] = row[q * 64 + lane];  // 256B/inst

    int res = 0;
    for (int t = 0; t < K_TOP; ++t) {
        float lm = v[0];
        int lq = 0;
        #pragma unroll
        for (int q = 1; q < NODES / 64; ++q) {
            bool g = v[q] > lm;
            lm = g ? v[q] : lm;
            lq = g ? q : lq;
        }
        float bv = lm;
        int bj = lq * 64 + lane;
        #pragma unroll
        for (int off = 32; off; off >>= 1) {
            float ov = __shfl_xor(bv, off, 64);
            int   oj = __shfl_xor(bj, off, 64);
            if (ov > bv || (ov == bv && oj < bj)) { bv = ov; bj = oj; }
        }
        if (lane == t) res = bj;
        const int wl = bj & 63, wq = bj >> 6;
        #pragma unroll
        for (int q = 0; q < NODES / 64; ++q)
            if (q == wq && lane == wl) v[q] = NEGINF;
    }
    if (lane < K_TOP) topk[i * K_TOP + lane] = res;
}

// ---------------------------------------------------------------------------
// K4: xl = x @ lin_w ; a_i/a_j per node (fused). One wave per output row.
// ---------------------------------------------------------------------------
__global__ __launch_bounds__(256) void lin_kernel(const float* __restrict__ x,
                                                  const float* __restrict__ lin_w,
                                                  const float* __restrict__ emb,
                                                  const float* __restrict__ att_i,
                                                  const float* __restrict__ att_j,
                                                  const float* __restrict__ att_em_i,
                                                  const float* __restrict__ att_em_j,
                                                  float* __restrict__ xl,
                                                  float* __restrict__ ai,
                                                  float* __restrict__ aj) {
    __shared__ float lw[DIM * DIM];   // 16 KiB
    __shared__ float xs[16 * DIM];    // 4 KiB
    const int tid = threadIdx.x;
    const int wave = tid >> 6;
    const int lane = tid & 63;
    const int row0 = blockIdx.x * 16;

    for (int t = tid; t < DIM * DIM; t += 256) lw[t] = lin_w[t];
    for (int t = tid; t < 16 * DIM; t += 256) xs[t] = x[row0 * DIM + t];
    __syncthreads();

    for (int rr = wave; rr < 16; rr += 4) {
        const int r = row0 + rr;
        float acc = 0.f;
        #pragma unroll
        for (int f = 0; f < DIM; ++f)
            acc = fmaf(xs[rr * DIM + f], lw[f * DIM + lane], acc);  // stride-64: 2/bank = free
        xl[r * DIM + lane] = acc;

        const int i = r & (NODES - 1);
        const float em = emb[i * DIM + lane];
        float ti = acc * att_i[lane] + em * att_em_i[lane];
        float tj = acc * att_j[lane] + em * att_em_j[lane];
        #pragma unroll
        for (int off = 32; off; off >>= 1) {
            ti += __shfl_xor(ti, off, 64);
            tj += __shfl_xor(tj, off, 64);
        }
        if (lane == 0) { ai[r] = ti; aj[r] = tj; }
    }
}

// ---------------------------------------------------------------------------
// K5: per-node fused GAT aggregate + BN1 + ReLU + emb-mul + BN2 + ReLU + readout
// one 64-lane wave per target node; lane == feature dim
// ---------------------------------------------------------------------------
__global__ __launch_bounds__(256) void agg_kernel(const int* __restrict__ topk,
                                                  const float* __restrict__ xl,
                                                  const float* __restrict__ ai,
                                                  const float* __restrict__ aj,
                                                  const float* __restrict__ emb,
                                                  const float* __restrict__ gnn_bias,
                                                  const float* __restrict__ g1, const float* __restrict__ b1,
                                                  const float* __restrict__ m1, const float* __restrict__ v1,
                                                  const float* __restrict__ g2, const float* __restrict__ b2,
                                                  const float* __restrict__ m2, const float* __restrict__ v2,
                                                  const float* __restrict__ out_w,
                                                  const float* __restrict__ out_b,
                                                  float* __restrict__ y) {
    const int e = blockIdx.x * 4 + (threadIdx.x >> 6);
    const int lane = threadIdx.x & 63;
    const int i = e & (NODES - 1);
    const int b = e >> 11;

    const float a_ie = ai[e];
    int nbr = 0;
    float raw = NEGINF;
    if (lane < K_TOP) {
        nbr = (b << 11) + topk[i * K_TOP + lane];
        float r0 = a_ie + aj[nbr];
        raw = (r0 >= 0.f) ? r0 : 0.2f * r0;   // leaky_relu(0.2)
    }
    float m = raw;
    #pragma unroll
    for (int off = 32; off; off >>= 1) m = fmaxf(m, __shfl_xor(m, off, 64));
    float p = (lane < K_TOP) ? __expf(raw - m) : 0.f;
    float s = p;
    #pragma unroll
    for (int off = 32; off; off >>= 1) s += __shfl_xor(s, off, 64);
    const float inv = 1.f / s;

    float acc = 0.f;
    #pragma unroll
    for (int k = 0; k < K_TOP; ++k) {
        const float pk = __shfl(p, k, 64);
        const int nb = __shfl(nbr, k, 64);
        acc = fmaf(pk, xl[nb * DIM + lane], acc);  // 256B coalesced gather, L2-resident
    }

    float o = acc * inv + gnn_bias[lane];
    o = (o - m1[lane]) * rsqrtf(v1[lane] + EPS) * g1[lane] + b1[lane];
    o = fmaxf(o, 0.f);
    float h = o * emb[i * DIM + lane];
    h = (h - m2[lane]) * rsqrtf(v2[lane] + EPS) * g2[lane] + b2[lane];
    h = fmaxf(h, 0.f);
    float t = h * out_w[lane];
    #pragma unroll
    for (int off = 32; off; off >>= 1) t += __shfl_xor(t, off, 64);
    if (lane == 0) y[e] = t + out_b[0];
}

// ---------------------------------------------------------------------------
extern "C" void kernel_launch(void* const* d_in, const int* in_sizes, int n_in,
                              void* d_out, int out_size, void* d_ws, size_t ws_size,
                              hipStream_t stream) {
    const float* data      = (const float*)d_in[0];
    // d_in[1] org_edge_index: unused (prior_graph dynamic top-k path)
    const float* emb       = (const float*)d_in[2];
    const float* lin_w     = (const float*)d_in[3];
    const float* att_i     = (const float*)d_in[4];
    const float* att_j     = (const float*)d_in[5];
    const float* att_em_i  = (const float*)d_in[6];
    const float* att_em_j  = (const float*)d_in[7];
    const float* gnn_bias  = (const float*)d_in[8];
    const float* bn1_gamma = (const float*)d_in[9];
    const float* bn1_beta  = (const float*)d_in[10];
    const float* bn1_mean  = (const float*)d_in[11];
    const float* bn1_var   = (const float*)d_in[12];
    const float* bn2_gamma = (const float*)d_in[13];
    const float* bn2_beta  = (const float*)d_in[14];
    const float* bn2_mean  = (const float*)d_in[15];
    const float* bn2_var   = (const float*)d_in[16];
    const float* out_w     = (const float*)d_in[17];
    const float* out_b     = (const float*)d_in[18];
    float* y = (float*)d_out;

    // workspace layout (bytes). cosm (16 MiB) is consumed by topk_kernel
    // BEFORE lin_kernel runs (same stream, serialized), so xl/ai/aj overlay it.
    char* ws = (char*)d_ws;
    float* cosm = (float*)(ws);                                  // 16 MiB (transient)
    float* xl   = (float*)(ws);                                  // 8 MiB, overlays cosm
    float* ai   = (float*)(ws + 8 * 1024 * 1024);                // 128 KiB
    float* aj   = (float*)(ws + 8 * 1024 * 1024 + 131072);       // 128 KiB
    float* wn   = (float*)(ws + 16 * 1024 * 1024);               // 512 KiB
    int*   topk = (int*)  (ws + 16 * 1024 * 1024 + 524288);      // 240 KiB

    normalize_kernel<<<NODES / 4, 256, 0, stream>>>(emb, wn);
    cos_kernel<<<dim3(NODES / TB, NODES / TB), 256, 0, stream>>>(wn, cosm);
    topk_kernel<<<NODES / 4, 256, 0, stream>>>(cosm, topk);
    lin_kernel<<<BN / 16, 256, 0, stream>>>(data, lin_w, emb, att_i, att_j,
                                            att_em_i, att_em_j, xl, ai, aj);
    agg_kernel<<<BN / 4, 256, 0, stream>>>(topk, xl, ai, aj, emb, gnn_bias,
                                           bn1_gamma, bn1_beta, bn1_mean, bn1_var,
                                           bn2_gamma, bn2_beta, bn2_mean, bn2_var,
                                           out_w, out_b, y);
}

// Round 7
// 178.829 us; speedup vs baseline: 1.6890x; 1.1348x over previous
//
#include <hip/hip_runtime.h>
#include <hip/hip_bf16.h>

#define NODES 2048
#define DIM   64
#define K_TOP 30
#define BATCH 16
#define BN    (NODES * BATCH)
#define NEGINF (-3.402823466e38f)
#define EPS 1e-5f
#define TB 64   // cos GEMM tile

// ---------------------------------------------------------------------------
// DPP wave64 reduction helpers (rocPRIM pattern: row_shr 1/2/4/8 +
// row_bcast15 + row_bcast31, result in lane 63, broadcast via readlane).
// VALU-latency cross-lane (~12 cyc/step) vs ds_bpermute shuffles (~65 cyc).
// ---------------------------------------------------------------------------
template <int CTRL>
__device__ __forceinline__ float dpp_add_f32(float x) {
    // bound_ctrl=true: invalid source lane contributes 0.0f (no double count)
    int y = __builtin_amdgcn_update_dpp(0, __float_as_int(x), CTRL, 0xf, 0xf, true);
    return x + __int_as_float(y);
}

__device__ __forceinline__ float wave_sum(float x) {
    x = dpp_add_f32<0x111>(x);   // row_shr:1
    x = dpp_add_f32<0x112>(x);   // row_shr:2
    x = dpp_add_f32<0x114>(x);   // row_shr:4
    x = dpp_add_f32<0x118>(x);   // row_shr:8  -> lane15 of each row = row sum
    x = dpp_add_f32<0x142>(x);   // row_bcast15
    x = dpp_add_f32<0x143>(x);   // row_bcast31 -> lane63 = wave sum
    return __int_as_float(__builtin_amdgcn_readlane(__float_as_int(x), 63));
}

template <int CTRL>
__device__ __forceinline__ float dpp_max_f32(float x) {
    // bound_ctrl=false: invalid source lane yields old (self) -> no-op for max
    int y = __builtin_amdgcn_update_dpp(__float_as_int(x), __float_as_int(x),
                                        CTRL, 0xf, 0xf, false);
    return fmaxf(x, __int_as_float(y));
}

__device__ __forceinline__ float wave_max(float x) {
    x = dpp_max_f32<0x111>(x);
    x = dpp_max_f32<0x112>(x);
    x = dpp_max_f32<0x114>(x);
    x = dpp_max_f32<0x118>(x);
    x = dpp_max_f32<0x142>(x);
    x = dpp_max_f32<0x143>(x);
    return __int_as_float(__builtin_amdgcn_readlane(__float_as_int(x), 63));
}

// lexicographic (value desc, index asc) argmax step on a (bv,bj) pair
#define ARGMAX_STEP(CTRL)                                                       \
    do {                                                                        \
        int nv_ = __builtin_amdgcn_update_dpp(__float_as_int(bv),               \
                      __float_as_int(bv), (CTRL), 0xf, 0xf, false);             \
        int nj_ = __builtin_amdgcn_update_dpp(bj, bj, (CTRL), 0xf, 0xf, false); \
        float nvf_ = __int_as_float(nv_);                                       \
        bool g_ = (nvf_ > bv) || (nvf_ == bv && nj_ < bj);                      \
        bv = g_ ? nvf_ : bv;                                                    \
        bj = g_ ? nj_ : bj;                                                     \
    } while (0)

// ---------------------------------------------------------------------------
// K1: normalized embedding  wn = w / ||w||_row   (one wave per row)
// ---------------------------------------------------------------------------
__global__ __launch_bounds__(256) void normalize_kernel(const float* __restrict__ w,
                                                        float* __restrict__ wn) {
    int r = blockIdx.x * 4 + (threadIdx.x >> 6);
    int lane = threadIdx.x & 63;
    float v = w[r * DIM + lane];
    float s = wave_sum(v * v);
    wn[r * DIM + lane] = v * rsqrtf(s);
}

// ---------------------------------------------------------------------------
// K2: cos = wn @ wn^T, LDS-tiled fp32 GEMM. 64x64 tile per block, 256 thr,
// 4x4 outputs/thread. All global reads cooperative/coalesced; LDS +1 pad.
// ---------------------------------------------------------------------------
__global__ __launch_bounds__(256) void cos_kernel(const float* __restrict__ wn,
                                                  float* __restrict__ cosm) {
    __shared__ float As[TB][DIM + 1];
    __shared__ float Bs[TB][DIM + 1];
    const int tid = threadIdx.x;
    const int bi = blockIdx.x, bj = blockIdx.y;

    for (int s = tid; s < TB * DIM; s += 256) {
        int r = s >> 6, d = s & 63;
        As[r][d] = wn[(bi * TB + r) * DIM + d];
        Bs[r][d] = wn[(bj * TB + r) * DIM + d];
    }
    __syncthreads();

    const int ti = tid >> 4, tj = tid & 15;
    float acc[4][4] = {};
    #pragma unroll 16
    for (int k = 0; k < DIM; ++k) {
        float a[4], b[4];
        #pragma unroll
        for (int u = 0; u < 4; ++u) a[u] = As[ti * 4 + u][k];
        #pragma unroll
        for (int v = 0; v < 4; ++v) b[v] = Bs[tj * 4 + v][k];
        #pragma unroll
        for (int u = 0; u < 4; ++u)
            #pragma unroll
            for (int v = 0; v < 4; ++v)
                acc[u][v] = fmaf(a[u], b[v], acc[u][v]);
    }
    #pragma unroll
    for (int u = 0; u < 4; ++u) {
        float4 o = make_float4(acc[u][0], acc[u][1], acc[u][2], acc[u][3]);
        *(float4*)&cosm[(size_t)(bi * TB + ti * 4 + u) * NODES + bj * TB + tj * 4] = o;
    }
}

// ---------------------------------------------------------------------------
// K3: top-30 per row. One wave per row; coalesced row load into 32 regs/lane,
// then 30 extractions, each a DPP argmax (VALU-latency, no LDS pipe) +
// scalar-branch removal (wq is SGPR-uniform from readlane -> q==wq is SALU).
// Tie-break: lower index wins (lax.top_k). Result order irrelevant downstream.
// ---------------------------------------------------------------------------
__global__ __launch_bounds__(256) void topk_kernel(const float* __restrict__ cosm,
                                                   int* __restrict__ topk) {
    const int i = blockIdx.x * 4 + (threadIdx.x >> 6);
    const int lane = threadIdx.x & 63;
    const float* row = cosm + (size_t)i * NODES;

    float v[NODES / 64];
    #pragma unroll
    for (int q = 0; q < NODES / 64; ++q) v[q] = row[q * 64 + lane];  // 256B/inst

    int res = 0;
    for (int t = 0; t < K_TOP; ++t) {
        // lane-local argmax over 32 regs (static unroll; lowest q on tie)
        float lm = v[0];
        int lq = 0;
        #pragma unroll
        for (int q = 1; q < NODES / 64; ++q) {
            bool g = v[q] > lm;
            lm = g ? v[q] : lm;
            lq = g ? q : lq;
        }
        float bv = lm;
        int bj = lq * 64 + lane;
        // wave argmax via DPP (ties -> lower j)
        ARGMAX_STEP(0x111);  // row_shr:1
        ARGMAX_STEP(0x112);  // row_shr:2
        ARGMAX_STEP(0x114);  // row_shr:4
        ARGMAX_STEP(0x118);  // row_shr:8
        ARGMAX_STEP(0x142);  // row_bcast15
        ARGMAX_STEP(0x143);  // row_bcast31 -> lane63 holds winner
        const int wj = __builtin_amdgcn_readlane(bj, 63);   // SGPR-uniform
        res = (lane == t) ? wj : res;
        const int wl = wj & 63;
        const int wq = wj >> 6;
        #pragma unroll
        for (int q = 0; q < NODES / 64; ++q)
            if (q == wq && lane == wl) v[q] = NEGINF;  // q==wq: scalar branch
    }
    if (lane < K_TOP) topk[i * K_TOP + lane] = res;
}

// ---------------------------------------------------------------------------
// K4: xl = x @ lin_w ; a_i/a_j per node (fused). One wave per output row.
// ---------------------------------------------------------------------------
__global__ __launch_bounds__(256) void lin_kernel(const float* __restrict__ x,
                                                  const float* __restrict__ lin_w,
                                                  const float* __restrict__ emb,
                                                  const float* __restrict__ att_i,
                                                  const float* __restrict__ att_j,
                                                  const float* __restrict__ att_em_i,
                                                  const float* __restrict__ att_em_j,
                                                  float* __restrict__ xl,
                                                  float* __restrict__ ai,
                                                  float* __restrict__ aj) {
    __shared__ float lw[DIM * DIM];   // 16 KiB
    __shared__ float xs[16 * DIM];    // 4 KiB
    const int tid = threadIdx.x;
    const int wave = tid >> 6;
    const int lane = tid & 63;
    const int row0 = blockIdx.x * 16;

    for (int t = tid; t < DIM * DIM; t += 256) lw[t] = lin_w[t];
    for (int t = tid; t < 16 * DIM; t += 256) xs[t] = x[row0 * DIM + t];
    __syncthreads();

    for (int rr = wave; rr < 16; rr += 4) {
        const int r = row0 + rr;
        float acc = 0.f;
        #pragma unroll
        for (int f = 0; f < DIM; ++f)
            acc = fmaf(xs[rr * DIM + f], lw[f * DIM + lane], acc);  // stride-64: 2/bank = free
        xl[r * DIM + lane] = acc;

        const int i = r & (NODES - 1);
        const float em = emb[i * DIM + lane];
        float ti = wave_sum(acc * att_i[lane] + em * att_em_i[lane]);
        float tj = wave_sum(acc * att_j[lane] + em * att_em_j[lane]);
        if (lane == 0) { ai[r] = ti; aj[r] = tj; }
    }
}

// ---------------------------------------------------------------------------
// K5: per-node fused GAT aggregate + BN1 + ReLU + emb-mul + BN2 + ReLU + readout
// one 64-lane wave per target node; lane == feature dim. Broadcasts via
// readlane (SALU, uniform SGPR gather base) instead of ds-pipe shuffles.
// ---------------------------------------------------------------------------
__global__ __launch_bounds__(256) void agg_kernel(const int* __restrict__ topk,
                                                  const float* __restrict__ xl,
                                                  const float* __restrict__ ai,
                                                  const float* __restrict__ aj,
                                                  const float* __restrict__ emb,
                                                  const float* __restrict__ gnn_bias,
                                                  const float* __restrict__ g1, const float* __restrict__ b1,
                                                  const float* __restrict__ m1, const float* __restrict__ v1,
                                                  const float* __restrict__ g2, const float* __restrict__ b2,
                                                  const float* __restrict__ m2, const float* __restrict__ v2,
                                                  const float* __restrict__ out_w,
                                                  const float* __restrict__ out_b,
                                                  float* __restrict__ y) {
    const int e = blockIdx.x * 4 + (threadIdx.x >> 6);
    const int lane = threadIdx.x & 63;
    const int i = e & (NODES - 1);
    const int b = e >> 11;

    const float a_ie = ai[e];
    int nbr = 0;
    float raw = NEGINF;
    if (lane < K_TOP) {
        nbr = (b << 11) + topk[i * K_TOP + lane];
        float r0 = a_ie + aj[nbr];
        raw = (r0 >= 0.f) ? r0 : 0.2f * r0;   // leaky_relu(0.2)
    }
    const float m = wave_max(raw);
    float p = (lane < K_TOP) ? __expf(raw - m) : 0.f;
    const float s = wave_sum(p);
    const float inv = 1.f / s;

    float acc = 0.f;
    #pragma unroll
    for (int k = 0; k < K_TOP; ++k) {
        const float pk = __int_as_float(__builtin_amdgcn_readlane(__float_as_int(p), k));
        const int nb = __builtin_amdgcn_readlane(nbr, k);   // SGPR -> uniform base
        acc = fmaf(pk, xl[nb * DIM + lane], acc);           // 256B coalesced gather
    }

    float o = acc * inv + gnn_bias[lane];
    o = (o - m1[lane]) * rsqrtf(v1[lane] + EPS) * g1[lane] + b1[lane];
    o = fmaxf(o, 0.f);
    float h = o * emb[i * DIM + lane];
    h = (h - m2[lane]) * rsqrtf(v2[lane] + EPS) * g2[lane] + b2[lane];
    h = fmaxf(h, 0.f);
    float t = wave_sum(h * out_w[lane]);
    if (lane == 0) y[e] = t + out_b[0];
}

// ---------------------------------------------------------------------------
extern "C" void kernel_launch(void* const* d_in, const int* in_sizes, int n_in,
                              void* d_out, int out_size, void* d_ws, size_t ws_size,
                              hipStream_t stream) {
    const float* data      = (const float*)d_in[0];
    // d_in[1] org_edge_index: unused (prior_graph dynamic top-k path)
    const float* emb       = (const float*)d_in[2];
    const float* lin_w     = (const float*)d_in[3];
    const float* att_i     = (const float*)d_in[4];
    const float* att_j     = (const float*)d_in[5];
    const float* att_em_i  = (const float*)d_in[6];
    const float* att_em_j  = (const float*)d_in[7];
    const float* gnn_bias  = (const float*)d_in[8];
    const float* bn1_gamma = (const float*)d_in[9];
    const float* bn1_beta  = (const float*)d_in[10];
    const float* bn1_mean  = (const float*)d_in[11];
    const float* bn1_var   = (const float*)d_in[12];
    const float* bn2_gamma = (const float*)d_in[13];
    const float* bn2_beta  = (const float*)d_in[14];
    const float* bn2_mean  = (const float*)d_in[15];
    const float* bn2_var   = (const float*)d_in[16];
    const float* out_w     = (const float*)d_in[17];
    const float* out_b     = (const float*)d_in[18];
    float* y = (float*)d_out;

    // workspace layout (bytes). cosm (16 MiB) is consumed by topk_kernel
    // BEFORE lin_kernel runs (same stream, serialized), so xl/ai/aj overlay it.
    char* ws = (char*)d_ws;
    float* cosm = (float*)(ws);                                  // 16 MiB (transient)
    float* xl   = (float*)(ws);                                  // 8 MiB, overlays cosm
    float* ai   = (float*)(ws + 8 * 1024 * 1024);                // 128 KiB
    float* aj   = (float*)(ws + 8 * 1024 * 1024 + 131072);       // 128 KiB
    float* wn   = (float*)(ws + 16 * 1024 * 1024);               // 512 KiB
    int*   topk = (int*)  (ws + 16 * 1024 * 1024 + 524288);      // 240 KiB

    normalize_kernel<<<NODES / 4, 256, 0, stream>>>(emb, wn);
    cos_kernel<<<dim3(NODES / TB, NODES / TB), 256, 0, stream>>>(wn, cosm);
    topk_kernel<<<NODES / 4, 256, 0, stream>>>(cosm, topk);
    lin_kernel<<<BN / 16, 256, 0, stream>>>(data, lin_w, emb, att_i, att_j,
                                            att_em_i, att_em_j, xl, ai, aj);
    agg_kernel<<<BN / 4, 256, 0, stream>>>(topk, xl, ai, aj, emb, gnn_bias,
                                           bn1_gamma, bn1_beta, bn1_mean, bn1_var,
                                           bn2_gamma, bn2_beta, bn2_mean, bn2_var,
                                           out_w, out_b, y);
}